// Round 4
// baseline (603.150 us; speedup 1.0000x reference)
//
#include <hip/hip_runtime.h>
#include <hip/hip_bf16.h>

typedef unsigned short ushort_t;
typedef unsigned int uint_t;

#define DIM   256
#define LSEQ  32768
#define HEADS 8
#define CPG   8
#define EPS   1e-5f

typedef float f32x4 __attribute__((ext_vector_type(4)));
typedef short sfrag8 __attribute__((ext_vector_type(8)));

static __device__ __forceinline__ float b2f(ushort_t u) {
    return __uint_as_float((uint_t)u << 16);
}
static __device__ __forceinline__ ushort_t f2bs(float f) {
    union { __hip_bfloat16 h; ushort_t u; } cv;
    cv.h = __float2bfloat16(f);
    return cv.u;
}

// ============ fused transpose + group stats (rebuilt: no scratch, vector loads) ============
// x fp32 [c][l] -> XT bf16 [l][c]; per-group sum/sumsq atomics.
// Block: 64 l-cols x 256 channels. Load float4/lane coalesced; LDS [c][l] stride 70.
__global__ __launch_bounds__(256) void k_tr(const float* __restrict__ x,
                                            ushort_t* __restrict__ XT,
                                            float* __restrict__ gsum,
                                            float* __restrict__ gsumsq) {
    __shared__ ushort_t lds[256 * 70];   // 35 KB
    const int tid   = threadIdx.x;
    const int l0    = blockIdx.x * 64;
    const int slot  = tid & 15;          // l_off = slot*4
    const int cbase = tid >> 4;          // 0..15

    float gs[16], gs2[16];
    #pragma unroll
    for (int i = 0; i < 16; i++) { gs[i] = 0.f; gs2[i] = 0.f; }

    #pragma unroll
    for (int i = 0; i < 16; i++) {
        int c = cbase + 16 * i;          // channel; group = 2i + (wave>>1), wave-uniform
        float4 v = *(const float4*)(x + (size_t)c * LSEQ + l0 + slot * 4);
        gs[i]  += v.x + v.y + v.z + v.w;
        gs2[i] += v.x*v.x + v.y*v.y + v.z*v.z + v.w*v.w;
        uint2 pk;
        pk.x = (uint_t)f2bs(v.x) | ((uint_t)f2bs(v.y) << 16);
        pk.y = (uint_t)f2bs(v.z) | ((uint_t)f2bs(v.w) << 16);
        *(uint2*)&lds[c * 70 + slot * 4] = pk;
    }

    // wave-reduce the 16 static group partials; lane 0 atomics
    const int b = (tid >> 6) >> 1;       // wave-uniform group offset bit
    #pragma unroll
    for (int i = 0; i < 16; i++) {
        float a = gs[i], s2 = gs2[i];
        for (int off = 32; off > 0; off >>= 1) {
            a  += __shfl_down(a, off);
            s2 += __shfl_down(s2, off);
        }
        if ((tid & 63) == 0) {
            atomicAdd(&gsum[2*i + b], a);
            atomicAdd(&gsumsq[2*i + b], s2);
        }
    }
    __syncthreads();

    // read out: thread: l_off = tid>>2, c0 = (tid&3)*64; 8 x uint4 (8 channels each)
    const int l_off = tid >> 2;
    const int c0    = (tid & 3) * 64;
    ushort_t* dst = XT + (size_t)(l0 + l_off) * 256 + c0;
    #pragma unroll
    for (int j = 0; j < 8; j++) {
        union { ushort_t s[8]; uint4 v; } pk;
        #pragma unroll
        for (int e = 0; e < 8; e++)
            pk.s[e] = lds[(c0 + 8*j + e) * 70 + l_off];
        *(uint4*)(dst + 8*j) = pk.v;
    }
}

// ============ a[c], bb[c] ============
__global__ void k_ab(const float* __restrict__ gn_w, const float* __restrict__ gn_b,
                     const float* __restrict__ gsum, const float* __restrict__ gsumsq,
                     float* __restrict__ A, float* __restrict__ BB) {
    int c = threadIdx.x;
    int g = c >> 3;
    const float inv_n = 1.f / (float)(CPG * LSEQ);
    float mu  = gsum[g] * inv_n;
    float var = gsumsq[g] * inv_n - mu * mu;
    float inv = rsqrtf(var + EPS);
    float a = gn_w[c] * inv;
    A[c]  = a;
    BB[c] = gn_b[c] - mu * a;
}

// ============ folded qkv biases ============
__global__ void k_fold_b(const float* __restrict__ w_qkv, const float* __restrict__ b_qkv,
                         const float* __restrict__ BB, float* __restrict__ BE) {
    int r = blockIdx.x * 256 + threadIdx.x;   // 1536
    float s = b_qkv[r];
    const float4* wr = (const float4*)(w_qkv + (size_t)r * DIM);
    const float4* bb = (const float4*)BB;
    #pragma unroll 4
    for (int c4 = 0; c4 < 64; c4++) {
        float4 w = wr[c4], b = bb[c4];
        s += w.x*b.x + w.y*b.y + w.z*b.z + w.w*b.w;
    }
    BE[r] = s;
}

// ============ folded k/v weights: WEB bf16 [r'][c], r' = h*128 + part*64 + j ============
__global__ void k_fold_w(const float* __restrict__ w_qkv, const float* __restrict__ A,
                         const float* __restrict__ BE,
                         ushort_t* __restrict__ WEB, float* __restrict__ BE2) {
    int idx = blockIdx.x * 256 + threadIdx.x;   // 262144
    int rp = idx >> 8, c = idx & 255;
    int h = rp >> 7, sub = rp & 127, part = sub >> 6, j = sub & 63;
    int orig = 512 + part * 512 + h * 64 + j;
    WEB[(size_t)rp * 256 + c] = f2bs(w_qkv[(size_t)orig * 256 + c] * A[c]);
    if (c == 0) BE2[rp] = BE[orig];
}

// ============ fused kv-GEMM + exp + context GEMM ============
// grid 512: h = bid>>6 (XCD-friendly: the 8 blocks sharing a superchunk are == mod 8
// -> same XCD -> XT tile served from that XCD's L2), superchunk = bid&63 (512 cols).
__global__ __launch_bounds__(256, 2) void k_attn(const ushort_t* __restrict__ XT,
                                                 const ushort_t* __restrict__ WEB,
                                                 const float* __restrict__ BE2,
                                                 float* __restrict__ S, float* __restrict__ Z) {
    __shared__ __align__(16) ushort_t xs[64 * 264];  // 64 cols x 256 ch
    __shared__ __align__(16) ushort_t ek[64 * 72];
    __shared__ __align__(16) ushort_t vv[64 * 72];
    const int tid  = threadIdx.x;
    const int lane = tid & 63;
    const int wv   = __builtin_amdgcn_readfirstlane(tid >> 6);
    const int ln   = lane & 15;
    const int q    = lane >> 4;
    const int mh   = wv >> 1;    // 0 -> k rows, 1 -> v rows
    const int nh   = wv & 1;     // 32-col half
    const int h    = blockIdx.x >> 6;
    const int cg0  = (blockIdx.x & 63) * 512;

    sfrag8 Af[4][8];
    #pragma unroll
    for (int mt = 0; mt < 4; mt++) {
        const ushort_t* ap = WEB + (size_t)(h*128 + mh*64 + mt*16 + ln) * 256 + q*8;
        #pragma unroll
        for (int k0 = 0; k0 < 8; k0++) Af[mt][k0] = *(const sfrag8*)(ap + k0*32);
    }
    float bias[4][4];
    #pragma unroll
    for (int mt = 0; mt < 4; mt++)
        #pragma unroll
        for (int r = 0; r < 4; r++)
            bias[mt][r] = BE2[h*128 + mh*64 + mt*16 + q*4 + r];

    f32x4 Sacc[4];
    #pragma unroll
    for (int nt = 0; nt < 4; nt++)
        #pragma unroll
        for (int e = 0; e < 4; e++) Sacc[nt][e] = 0.f;
    float zsum = 0.f;

    for (int sc = 0; sc < 8; sc++) {
        const int l0 = cg0 + sc * 64;
        #pragma unroll
        for (int it = 0; it < 8; it++) {
            int idx = it * 256 + tid;
            int row = idx >> 5, seg = idx & 31;
            *(uint4*)&xs[row * 264 + seg * 8] =
                *(const uint4*)(XT + (size_t)(l0 + row) * 256 + seg * 8);
        }
        __syncthreads();

        f32x4 acc[4][2];
        #pragma unroll
        for (int mt = 0; mt < 4; mt++)
            #pragma unroll
            for (int nt = 0; nt < 2; nt++)
                #pragma unroll
                for (int e = 0; e < 4; e++) acc[mt][nt][e] = 0.f;

        #pragma unroll
        for (int k0 = 0; k0 < 8; k0++) {
            sfrag8 b0 = *(const sfrag8*)&xs[(nh*32 + ln)      * 264 + k0*32 + q*8];
            sfrag8 b1 = *(const sfrag8*)&xs[(nh*32 + 16 + ln) * 264 + k0*32 + q*8];
            #pragma unroll
            for (int mt = 0; mt < 4; mt++) {
                acc[mt][0] = __builtin_amdgcn_mfma_f32_16x16x32_bf16(Af[mt][k0], b0, acc[mt][0], 0, 0, 0);
                acc[mt][1] = __builtin_amdgcn_mfma_f32_16x16x32_bf16(Af[mt][k0], b1, acc[mt][1], 0, 0, 0);
            }
        }

        if (mh == 0) {
            #pragma unroll
            for (int mt = 0; mt < 4; mt++)
                #pragma unroll
                for (int nt = 0; nt < 2; nt++)
                    #pragma unroll
                    for (int r = 0; r < 4; r++) {
                        int row = mt*16 + q*4 + r;
                        int col = nh*32 + nt*16 + ln;
                        ek[row * 72 + col] = f2bs(__expf(acc[mt][nt][r] + bias[mt][r]));
                    }
        } else {
            #pragma unroll
            for (int mt = 0; mt < 4; mt++)
                #pragma unroll
                for (int nt = 0; nt < 2; nt++)
                    #pragma unroll
                    for (int r = 0; r < 4; r++) {
                        int row = mt*16 + q*4 + r;
                        int col = nh*32 + nt*16 + ln;
                        vv[row * 72 + col] = f2bs(acc[mt][nt][r] + bias[mt][r]);
                    }
        }
        __syncthreads();

        #pragma unroll
        for (int k0 = 0; k0 < 2; k0++) {
            sfrag8 a = *(const sfrag8*)&ek[(wv*16 + ln) * 72 + k0*32 + q*8];
            #pragma unroll
            for (int nt = 0; nt < 4; nt++) {
                sfrag8 b = *(const sfrag8*)&vv[(nt*16 + ln) * 72 + k0*32 + q*8];
                Sacc[nt] = __builtin_amdgcn_mfma_f32_16x16x32_bf16(a, b, Sacc[nt], 0, 0, 0);
            }
        }
        if (wv == 2) {
            float zs = 0.f;
            #pragma unroll 8
            for (int j = 0; j < 64; j++) zs += b2f(ek[lane * 72 + j]);
            zsum += zs;
        }
    }

    float* Sh = S + h * 4096;
    #pragma unroll
    for (int nt = 0; nt < 4; nt++)
        #pragma unroll
        for (int r = 0; r < 4; r++)
            atomicAdd(&Sh[(wv*16 + q*4 + r) * 64 + nt*16 + ln], Sacc[nt][r]);
    if (wv == 2) atomicAdd(&Z[h * 64 + lane], zsum);
}

// ============ W2[d][hc] = sum_e w_out[d][h64+e] * S[hc][e] / Z[hc] ============
__global__ void k_w2(const float* __restrict__ w_out, const float* __restrict__ S,
                     const float* __restrict__ Z, float* __restrict__ W2) {
    int d  = blockIdx.x >> 1;
    int hc = ((blockIdx.x & 1) << 8) + threadIdx.x;
    int h64 = hc & ~63;
    float invZ = 1.f / Z[hc];
    const float4* wo = (const float4*)(w_out + (size_t)d * 512 + h64);
    const float4* Sr = (const float4*)(S + (size_t)hc * 64);
    float s = 0.f;
    #pragma unroll
    for (int e4 = 0; e4 < 16; e4++) {
        float4 a = wo[e4], b = Sr[e4];
        s += a.x*b.x + a.y*b.y + a.z*b.z + a.w*b.w;
    }
    W2[(size_t)d * 512 + hc] = s * invZ;
}

// ============ W3B[d][c] bf16 + B3[d] ============
__global__ void k_w3(const float* __restrict__ w_qkv, const float* __restrict__ W2,
                     const float* __restrict__ A, const float* __restrict__ BE,
                     const float* __restrict__ b_out,
                     ushort_t* __restrict__ W3B, float* __restrict__ B3) {
    int d = blockIdx.x, c = threadIdx.x;
    const float* W2d = W2 + (size_t)d * 512;
    float s = 0.f;
    #pragma unroll 4
    for (int hc = 0; hc < 512; hc++)
        s += W2d[hc] * w_qkv[(size_t)hc * 256 + c];
    W3B[(size_t)d * 256 + c] = f2bs(s * A[c]);
    __shared__ float red[256];
    red[c] = W2d[c] * BE[c] + W2d[256 + c] * BE[256 + c];
    __syncthreads();
    for (int off = 128; off > 0; off >>= 1) {
        if (c < off) red[c] += red[c + off];
        __syncthreads();
    }
    if (c == 0) B3[d] = b_out[d] + red[0];
}

// ============ final GEMM: out = W3B @ xT + b3 ============
// grid 1024: m0 = bid>>9 (the two m-half blocks of a tile are == mod 8 -> same XCD),
// 64-col chunk = bid&511.
__global__ __launch_bounds__(256, 2) void k_final(const ushort_t* __restrict__ XT,
                                                  const ushort_t* __restrict__ W3B,
                                                  const float* __restrict__ B3,
                                                  float* __restrict__ out) {
    __shared__ __align__(16) ushort_t xs[64 * 264];
    const int tid  = threadIdx.x;
    const int lane = tid & 63;
    const int wv   = __builtin_amdgcn_readfirstlane(tid >> 6);
    const int ln   = lane & 15;
    const int q    = lane >> 4;
    const int mh   = wv >> 1;
    const int nh   = wv & 1;
    const int m0   = (blockIdx.x >> 9) * 128;
    const int l0   = (blockIdx.x & 511) * 64;

    sfrag8 Af[4][8];
    #pragma unroll
    for (int mt = 0; mt < 4; mt++) {
        const ushort_t* ap = W3B + (size_t)(m0 + mh*64 + mt*16 + ln) * 256 + q*8;
        #pragma unroll
        for (int k0 = 0; k0 < 8; k0++) Af[mt][k0] = *(const sfrag8*)(ap + k0*32);
    }
    float bias[4][4];
    #pragma unroll
    for (int mt = 0; mt < 4; mt++)
        #pragma unroll
        for (int r = 0; r < 4; r++)
            bias[mt][r] = B3[m0 + mh*64 + mt*16 + q*4 + r];

    #pragma unroll
    for (int it = 0; it < 8; it++) {
        int idx = it * 256 + tid;
        int row = idx >> 5, seg = idx & 31;
        *(uint4*)&xs[row * 264 + seg * 8] =
            *(const uint4*)(XT + (size_t)(l0 + row) * 256 + seg * 8);
    }
    __syncthreads();

    f32x4 acc[4][2];
    #pragma unroll
    for (int mt = 0; mt < 4; mt++)
        #pragma unroll
        for (int nt = 0; nt < 2; nt++)
            #pragma unroll
            for (int e = 0; e < 4; e++) acc[mt][nt][e] = 0.f;

    #pragma unroll
    for (int k0 = 0; k0 < 8; k0++) {
        sfrag8 b0 = *(const sfrag8*)&xs[(nh*32 + ln)      * 264 + k0*32 + q*8];
        sfrag8 b1 = *(const sfrag8*)&xs[(nh*32 + 16 + ln) * 264 + k0*32 + q*8];
        #pragma unroll
        for (int mt = 0; mt < 4; mt++) {
            acc[mt][0] = __builtin_amdgcn_mfma_f32_16x16x32_bf16(Af[mt][k0], b0, acc[mt][0], 0, 0, 0);
            acc[mt][1] = __builtin_amdgcn_mfma_f32_16x16x32_bf16(Af[mt][k0], b1, acc[mt][1], 0, 0, 0);
        }
    }

    #pragma unroll
    for (int mt = 0; mt < 4; mt++)
        #pragma unroll
        for (int nt = 0; nt < 2; nt++)
            #pragma unroll
            for (int r = 0; r < 4; r++) {
                int row = m0 + mh*64 + mt*16 + q*4 + r;
                int col = l0 + nh*32 + nt*16 + ln;
                out[(size_t)row * LSEQ + col] = acc[mt][nt][r] + bias[mt][r];
            }
}

// ============ launch ============
extern "C" void kernel_launch(void* const* d_in, const int* in_sizes, int n_in,
                              void* d_out, int out_size, void* d_ws, size_t ws_size,
                              hipStream_t stream) {
    const float* x     = (const float*)d_in[0];
    const float* gn_w  = (const float*)d_in[1];
    const float* gn_b  = (const float*)d_in[2];
    const float* w_qkv = (const float*)d_in[3];
    const float* b_qkv = (const float*)d_in[4];
    const float* w_out = (const float*)d_in[5];
    const float* b_out = (const float*)d_in[6];
    float* out = (float*)d_out;
    float* ws  = (float*)d_ws;

    float*    gsum   = ws + 0;        // 32
    float*    gsumsq = ws + 32;       // 32
    float*    S      = ws + 64;       // 32768
    float*    Z      = ws + 32832;    // 512   [zeroed through 33344]
    float*    A      = ws + 33344;    // 256
    float*    BB     = ws + 33600;    // 256
    float*    BE     = ws + 33856;    // 1536
    float*    BE2    = ws + 35392;    // 1024
    ushort_t* WEB    = (ushort_t*)(ws + 36416);    // 1024*256 bf16 (65536 f)
    float*    W2     = ws + 101952;   // 131072
    ushort_t* W3B    = (ushort_t*)(ws + 233024);   // 256*256 bf16 (32768 f)
    float*    B3     = ws + 265792;   // 256
    ushort_t* XT     = (ushort_t*)(ws + 266048);   // 32768*256 bf16 (4194304 f)

    hipMemsetAsync(ws, 0, 33344 * sizeof(float), stream);   // gsum, gsumsq, S, Z
    k_tr    <<<512,  256, 0, stream>>>(x, XT, gsum, gsumsq);
    k_ab    <<<1,    256, 0, stream>>>(gn_w, gn_b, gsum, gsumsq, A, BB);
    k_fold_b<<<6,    256, 0, stream>>>(w_qkv, b_qkv, BB, BE);
    k_fold_w<<<1024, 256, 0, stream>>>(w_qkv, A, BE, WEB, BE2);
    k_attn  <<<512,  256, 0, stream>>>(XT, WEB, BE2, S, Z);
    k_w2    <<<512,  256, 0, stream>>>(w_out, S, Z, W2);
    k_w3    <<<256,  256, 0, stream>>>(w_qkv, W2, A, BE, b_out, W3B, B3);
    k_final <<<1024, 256, 0, stream>>>(XT, W3B, B3, out);
}

// Round 5
// 253.043 us; speedup vs baseline: 2.3836x; 2.3836x over previous
//
#include <hip/hip_runtime.h>
#include <hip/hip_bf16.h>

typedef unsigned short ushort_t;
typedef unsigned int uint_t;

#define DIM   256
#define LSEQ  32768
#define HEADS 8
#define CPG   8
#define EPS   1e-5f

typedef float f32x4 __attribute__((ext_vector_type(4)));
typedef short sfrag8 __attribute__((ext_vector_type(8)));

static __device__ __forceinline__ float b2f(ushort_t u) {
    return __uint_as_float((uint_t)u << 16);
}
static __device__ __forceinline__ ushort_t f2bs(float f) {
    union { __hip_bfloat16 h; ushort_t u; } cv;
    cv.h = __float2bfloat16(f);
    return cv.u;
}
static __device__ __forceinline__ uint_t pk2(float a, float b) {
    return (uint_t)f2bs(a) | ((uint_t)f2bs(b) << 16);
}

// ============ fused transpose + group stats: pure-register 4x4 micro-transpose ============
// x fp32 [c][l] -> XT bf16 [l][c]. No LDS, no indexed arrays (scratch-proof).
// Block tile: 128 l x 128 c. Wave w: c-range [c0+32w, +32); 4 l-iterations of 32.
// Lane: l_blk = lane>>3 (0..7), c_blk = lane&7 (0..7); thread tile 4l x 4c.
__global__ __launch_bounds__(256) void k_tr(const float* __restrict__ x,
                                            ushort_t* __restrict__ XT,
                                            float* __restrict__ gsum,
                                            float* __restrict__ gsumsq) {
    const int tid   = threadIdx.x;
    const int lane  = tid & 63;
    const int wv    = tid >> 6;
    const int l_blk = lane >> 3;
    const int c_blk = lane & 7;
    const int c0    = (blockIdx.x & 1) * 128;
    const int l0b   = (blockIdx.x >> 1) * 128;
    const int cb    = c0 + 32 * wv + 4 * c_blk;   // this thread's first channel

    const float* xr0 = x + (size_t)(cb + 0) * LSEQ;
    const float* xr1 = x + (size_t)(cb + 1) * LSEQ;
    const float* xr2 = x + (size_t)(cb + 2) * LSEQ;
    const float* xr3 = x + (size_t)(cb + 3) * LSEQ;

    float s = 0.f, s2 = 0.f;

    #pragma unroll
    for (int t = 0; t < 4; t++) {
        const int l = l0b + 32 * t + 4 * l_blk;
        float4 a = *(const float4*)(xr0 + l);
        float4 b = *(const float4*)(xr1 + l);
        float4 c = *(const float4*)(xr2 + l);
        float4 d = *(const float4*)(xr3 + l);

        s  += (a.x + a.y + a.z + a.w) + (b.x + b.y + b.z + b.w)
            + (c.x + c.y + c.z + c.w) + (d.x + d.y + d.z + d.w);
        s2 += (a.x*a.x + a.y*a.y + a.z*a.z + a.w*a.w)
            + (b.x*b.x + b.y*b.y + b.z*b.z + b.w*b.w)
            + (c.x*c.x + c.y*c.y + c.z*c.z + c.w*c.w)
            + (d.x*d.x + d.y*d.y + d.z*d.z + d.w*d.w);

        ushort_t* dst = XT + (size_t)l * 256 + cb;
        uint2 p0; p0.x = pk2(a.x, b.x); p0.y = pk2(c.x, d.x);
        uint2 p1; p1.x = pk2(a.y, b.y); p1.y = pk2(c.y, d.y);
        uint2 p2; p2.x = pk2(a.z, b.z); p2.y = pk2(c.z, d.z);
        uint2 p3; p3.x = pk2(a.w, b.w); p3.y = pk2(c.w, d.w);
        *(uint2*)(dst)           = p0;
        *(uint2*)(dst + 256)     = p1;
        *(uint2*)(dst + 512)     = p2;
        *(uint2*)(dst + 768)     = p3;
    }

    // segmented reduce: sum over lanes sharing (c_blk>>1): xor lane bits 0 (c_blk lsb)
    // and 3,4,5 (l_blk). Each thread's 4 channels lie in one group (4-aligned span).
    s  += __shfl_xor(s, 1);   s2 += __shfl_xor(s2, 1);
    s  += __shfl_xor(s, 8);   s2 += __shfl_xor(s2, 8);
    s  += __shfl_xor(s, 16);  s2 += __shfl_xor(s2, 16);
    s  += __shfl_xor(s, 32);  s2 += __shfl_xor(s2, 32);
    if (l_blk == 0 && (c_blk & 1) == 0) {
        int g = ((c0 + 32 * wv) >> 3) + (c_blk >> 1);
        atomicAdd(&gsum[g], s);
        atomicAdd(&gsumsq[g], s2);
    }
}

// ============ a[c], bb[c] ============
__global__ void k_ab(const float* __restrict__ gn_w, const float* __restrict__ gn_b,
                     const float* __restrict__ gsum, const float* __restrict__ gsumsq,
                     float* __restrict__ A, float* __restrict__ BB) {
    int c = threadIdx.x;
    int g = c >> 3;
    const float inv_n = 1.f / (float)(CPG * LSEQ);
    float mu  = gsum[g] * inv_n;
    float var = gsumsq[g] * inv_n - mu * mu;
    float inv = rsqrtf(var + EPS);
    float a = gn_w[c] * inv;
    A[c]  = a;
    BB[c] = gn_b[c] - mu * a;
}

// ============ folded qkv biases ============
__global__ void k_fold_b(const float* __restrict__ w_qkv, const float* __restrict__ b_qkv,
                         const float* __restrict__ BB, float* __restrict__ BE) {
    int r = blockIdx.x * 256 + threadIdx.x;   // 1536
    float s = b_qkv[r];
    const float4* wr = (const float4*)(w_qkv + (size_t)r * DIM);
    const float4* bb = (const float4*)BB;
    #pragma unroll 4
    for (int c4 = 0; c4 < 64; c4++) {
        float4 w = wr[c4], b = bb[c4];
        s += w.x*b.x + w.y*b.y + w.z*b.z + w.w*b.w;
    }
    BE[r] = s;
}

// ============ folded k/v weights: WEB bf16 [r'][c], r' = h*128 + part*64 + j ============
__global__ void k_fold_w(const float* __restrict__ w_qkv, const float* __restrict__ A,
                         const float* __restrict__ BE,
                         ushort_t* __restrict__ WEB, float* __restrict__ BE2) {
    int idx = blockIdx.x * 256 + threadIdx.x;   // 262144
    int rp = idx >> 8, c = idx & 255;
    int h = rp >> 7, sub = rp & 127, part = sub >> 6, j = sub & 63;
    int orig = 512 + part * 512 + h * 64 + j;
    WEB[(size_t)rp * 256 + c] = f2bs(w_qkv[(size_t)orig * 256 + c] * A[c]);
    if (c == 0) BE2[rp] = BE[orig];
}

// ============ fused kv-GEMM + exp + context GEMM (register-prefetch pipeline) ============
// grid 512: h = bid>>6 (8 sharers of a superchunk are == mod 8 -> same XCD L2),
// superchunk = bid&63 (512 cols, 8 sub-chunks of 64).
__global__ __launch_bounds__(256, 2) void k_attn(const ushort_t* __restrict__ XT,
                                                 const ushort_t* __restrict__ WEB,
                                                 const float* __restrict__ BE2,
                                                 float* __restrict__ S, float* __restrict__ Z) {
    __shared__ __align__(16) ushort_t xs[64 * 264];
    __shared__ __align__(16) ushort_t ek[64 * 72];
    __shared__ __align__(16) ushort_t vv[64 * 72];
    const int tid  = threadIdx.x;
    const int lane = tid & 63;
    const int wv   = __builtin_amdgcn_readfirstlane(tid >> 6);
    const int ln   = lane & 15;
    const int q    = lane >> 4;
    const int mh   = wv >> 1;
    const int nh   = wv & 1;
    const int h    = blockIdx.x >> 6;
    const int cg0  = (blockIdx.x & 63) * 512;

    const int srow = tid >> 5;          // staging row base (0..7)
    const int sseg = (tid & 31) * 8;    // staging col segment

    sfrag8 Af[4][8];
    #pragma unroll
    for (int mt = 0; mt < 4; mt++) {
        const ushort_t* ap = WEB + (size_t)(h*128 + mh*64 + mt*16 + ln) * 256 + q*8;
        #pragma unroll
        for (int k0 = 0; k0 < 8; k0++) Af[mt][k0] = *(const sfrag8*)(ap + k0*32);
    }
    float bias[4][4];
    #pragma unroll
    for (int mt = 0; mt < 4; mt++)
        #pragma unroll
        for (int r = 0; r < 4; r++)
            bias[mt][r] = BE2[h*128 + mh*64 + mt*16 + q*4 + r];

    f32x4 Sacc[4];
    #pragma unroll
    for (int nt = 0; nt < 4; nt++)
        #pragma unroll
        for (int e = 0; e < 4; e++) Sacc[nt][e] = 0.f;
    float zsum = 0.f;

    // prefetch sub-chunk 0
    uint4 pf[8];
    #pragma unroll
    for (int it = 0; it < 8; it++)
        pf[it] = *(const uint4*)(XT + (size_t)(cg0 + it*8 + srow) * 256 + sseg);

    for (int sc = 0; sc < 8; sc++) {
        // write prefetched tile to LDS
        #pragma unroll
        for (int it = 0; it < 8; it++)
            *(uint4*)&xs[(it*8 + srow) * 264 + sseg] = pf[it];
        __syncthreads();

        // issue next sub-chunk's loads (latency overlapped with GEMM1/GEMM2)
        if (sc < 7) {
            const int l0n = cg0 + (sc + 1) * 64;
            #pragma unroll
            for (int it = 0; it < 8; it++)
                pf[it] = *(const uint4*)(XT + (size_t)(l0n + it*8 + srow) * 256 + sseg);
        }

        // GEMM1: 64 rows (4 m-tiles) x 32 cols (2 n-tiles), K=256
        f32x4 acc[4][2];
        #pragma unroll
        for (int mt = 0; mt < 4; mt++)
            #pragma unroll
            for (int nt = 0; nt < 2; nt++)
                #pragma unroll
                for (int e = 0; e < 4; e++) acc[mt][nt][e] = 0.f;

        #pragma unroll
        for (int k0 = 0; k0 < 8; k0++) {
            sfrag8 b0 = *(const sfrag8*)&xs[(nh*32 + ln)      * 264 + k0*32 + q*8];
            sfrag8 b1 = *(const sfrag8*)&xs[(nh*32 + 16 + ln) * 264 + k0*32 + q*8];
            #pragma unroll
            for (int mt = 0; mt < 4; mt++) {
                acc[mt][0] = __builtin_amdgcn_mfma_f32_16x16x32_bf16(Af[mt][k0], b0, acc[mt][0], 0, 0, 0);
                acc[mt][1] = __builtin_amdgcn_mfma_f32_16x16x32_bf16(Af[mt][k0], b1, acc[mt][1], 0, 0, 0);
            }
        }

        if (mh == 0) {
            #pragma unroll
            for (int mt = 0; mt < 4; mt++)
                #pragma unroll
                for (int nt = 0; nt < 2; nt++)
                    #pragma unroll
                    for (int r = 0; r < 4; r++) {
                        int row = mt*16 + q*4 + r;
                        int col = nh*32 + nt*16 + ln;
                        ek[row * 72 + col] = f2bs(__expf(acc[mt][nt][r] + bias[mt][r]));
                    }
        } else {
            #pragma unroll
            for (int mt = 0; mt < 4; mt++)
                #pragma unroll
                for (int nt = 0; nt < 2; nt++)
                    #pragma unroll
                    for (int r = 0; r < 4; r++) {
                        int row = mt*16 + q*4 + r;
                        int col = nh*32 + nt*16 + ln;
                        vv[row * 72 + col] = f2bs(acc[mt][nt][r] + bias[mt][r]);
                    }
        }
        __syncthreads();

        // GEMM2: S += ek @ vv^T (K=64)
        #pragma unroll
        for (int k0 = 0; k0 < 2; k0++) {
            sfrag8 a = *(const sfrag8*)&ek[(wv*16 + ln) * 72 + k0*32 + q*8];
            #pragma unroll
            for (int nt = 0; nt < 4; nt++) {
                sfrag8 b = *(const sfrag8*)&vv[(nt*16 + ln) * 72 + k0*32 + q*8];
                Sacc[nt] = __builtin_amdgcn_mfma_f32_16x16x32_bf16(a, b, Sacc[nt], 0, 0, 0);
            }
        }
        if (wv == 2) {
            float zs = 0.f;
            #pragma unroll 8
            for (int j = 0; j < 64; j++) zs += b2f(ek[lane * 72 + j]);
            zsum += zs;
        }
    }

    float* Sh = S + h * 4096;
    #pragma unroll
    for (int nt = 0; nt < 4; nt++)
        #pragma unroll
        for (int r = 0; r < 4; r++)
            atomicAdd(&Sh[(wv*16 + q*4 + r) * 64 + nt*16 + ln], Sacc[nt][r]);
    if (wv == 2) atomicAdd(&Z[h * 64 + lane], zsum);
}

// ============ W2[d][hc] = sum_e w_out[d][h64+e] * S[hc][e] / Z[hc] ============
__global__ void k_w2(const float* __restrict__ w_out, const float* __restrict__ S,
                     const float* __restrict__ Z, float* __restrict__ W2) {
    int d  = blockIdx.x >> 1;
    int hc = ((blockIdx.x & 1) << 8) + threadIdx.x;
    int h64 = hc & ~63;
    float invZ = 1.f / Z[hc];
    const float4* wo = (const float4*)(w_out + (size_t)d * 512 + h64);
    const float4* Sr = (const float4*)(S + (size_t)hc * 64);
    float s = 0.f;
    #pragma unroll
    for (int e4 = 0; e4 < 16; e4++) {
        float4 a = wo[e4], b = Sr[e4];
        s += a.x*b.x + a.y*b.y + a.z*b.z + a.w*b.w;
    }
    W2[(size_t)d * 512 + hc] = s * invZ;
}

// ============ W3B[d][c] bf16 + B3[d] ============
__global__ void k_w3(const float* __restrict__ w_qkv, const float* __restrict__ W2,
                     const float* __restrict__ A, const float* __restrict__ BE,
                     const float* __restrict__ b_out,
                     ushort_t* __restrict__ W3B, float* __restrict__ B3) {
    int d = blockIdx.x, c = threadIdx.x;
    const float* W2d = W2 + (size_t)d * 512;
    float s = 0.f;
    #pragma unroll 4
    for (int hc = 0; hc < 512; hc++)
        s += W2d[hc] * w_qkv[(size_t)hc * 256 + c];
    W3B[(size_t)d * 256 + c] = f2bs(s * A[c]);
    __shared__ float red[256];
    red[c] = W2d[c] * BE[c] + W2d[256 + c] * BE[256 + c];
    __syncthreads();
    for (int off = 128; off > 0; off >>= 1) {
        if (c < off) red[c] += red[c + off];
        __syncthreads();
    }
    if (c == 0) B3[d] = b_out[d] + red[0];
}

// ============ final GEMM: out = W3B @ xT + b3 ============
__global__ __launch_bounds__(256, 2) void k_final(const ushort_t* __restrict__ XT,
                                                  const ushort_t* __restrict__ W3B,
                                                  const float* __restrict__ B3,
                                                  float* __restrict__ out) {
    __shared__ __align__(16) ushort_t xs[64 * 264];
    const int tid  = threadIdx.x;
    const int lane = tid & 63;
    const int wv   = __builtin_amdgcn_readfirstlane(tid >> 6);
    const int ln   = lane & 15;
    const int q    = lane >> 4;
    const int mh   = wv >> 1;
    const int nh   = wv & 1;
    const int m0   = (blockIdx.x >> 9) * 128;
    const int l0   = (blockIdx.x & 511) * 64;

    sfrag8 Af[4][8];
    #pragma unroll
    for (int mt = 0; mt < 4; mt++) {
        const ushort_t* ap = W3B + (size_t)(m0 + mh*64 + mt*16 + ln) * 256 + q*8;
        #pragma unroll
        for (int k0 = 0; k0 < 8; k0++) Af[mt][k0] = *(const sfrag8*)(ap + k0*32);
    }
    float bias[4][4];
    #pragma unroll
    for (int mt = 0; mt < 4; mt++)
        #pragma unroll
        for (int r = 0; r < 4; r++)
            bias[mt][r] = B3[m0 + mh*64 + mt*16 + q*4 + r];

    #pragma unroll
    for (int it = 0; it < 8; it++) {
        int idx = it * 256 + tid;
        int row = idx >> 5, seg = idx & 31;
        *(uint4*)&xs[row * 264 + seg * 8] =
            *(const uint4*)(XT + (size_t)(l0 + row) * 256 + seg * 8);
    }
    __syncthreads();

    f32x4 acc[4][2];
    #pragma unroll
    for (int mt = 0; mt < 4; mt++)
        #pragma unroll
        for (int nt = 0; nt < 2; nt++)
            #pragma unroll
            for (int e = 0; e < 4; e++) acc[mt][nt][e] = 0.f;

    #pragma unroll
    for (int k0 = 0; k0 < 8; k0++) {
        sfrag8 b0 = *(const sfrag8*)&xs[(nh*32 + ln)      * 264 + k0*32 + q*8];
        sfrag8 b1 = *(const sfrag8*)&xs[(nh*32 + 16 + ln) * 264 + k0*32 + q*8];
        #pragma unroll
        for (int mt = 0; mt < 4; mt++) {
            acc[mt][0] = __builtin_amdgcn_mfma_f32_16x16x32_bf16(Af[mt][k0], b0, acc[mt][0], 0, 0, 0);
            acc[mt][1] = __builtin_amdgcn_mfma_f32_16x16x32_bf16(Af[mt][k0], b1, acc[mt][1], 0, 0, 0);
        }
    }

    #pragma unroll
    for (int mt = 0; mt < 4; mt++)
        #pragma unroll
        for (int nt = 0; nt < 2; nt++)
            #pragma unroll
            for (int r = 0; r < 4; r++) {
                int row = m0 + mh*64 + mt*16 + q*4 + r;
                int col = l0 + nh*32 + nt*16 + ln;
                out[(size_t)row * LSEQ + col] = acc[mt][nt][r] + bias[mt][r];
            }
}

// ============ launch ============
extern "C" void kernel_launch(void* const* d_in, const int* in_sizes, int n_in,
                              void* d_out, int out_size, void* d_ws, size_t ws_size,
                              hipStream_t stream) {
    const float* x     = (const float*)d_in[0];
    const float* gn_w  = (const float*)d_in[1];
    const float* gn_b  = (const float*)d_in[2];
    const float* w_qkv = (const float*)d_in[3];
    const float* b_qkv = (const float*)d_in[4];
    const float* w_out = (const float*)d_in[5];
    const float* b_out = (const float*)d_in[6];
    float* out = (float*)d_out;
    float* ws  = (float*)d_ws;

    float*    gsum   = ws + 0;        // 32
    float*    gsumsq = ws + 32;       // 32
    float*    S      = ws + 64;       // 32768
    float*    Z      = ws + 32832;    // 512   [zeroed through 33344]
    float*    A      = ws + 33344;    // 256
    float*    BB     = ws + 33600;    // 256
    float*    BE     = ws + 33856;    // 1536
    float*    BE2    = ws + 35392;    // 1024
    ushort_t* WEB    = (ushort_t*)(ws + 36416);    // 1024*256 bf16 (65536 f)
    float*    W2     = ws + 101952;   // 131072
    ushort_t* W3B    = (ushort_t*)(ws + 233024);   // 256*256 bf16 (32768 f)
    float*    B3     = ws + 265792;   // 256
    ushort_t* XT     = (ushort_t*)(ws + 266048);   // 32768*256 bf16 (4194304 f)

    hipMemsetAsync(ws, 0, 33344 * sizeof(float), stream);   // gsum, gsumsq, S, Z
    k_tr    <<<512,  256, 0, stream>>>(x, XT, gsum, gsumsq);
    k_ab    <<<1,    256, 0, stream>>>(gn_w, gn_b, gsum, gsumsq, A, BB);
    k_fold_b<<<6,    256, 0, stream>>>(w_qkv, b_qkv, BB, BE);
    k_fold_w<<<1024, 256, 0, stream>>>(w_qkv, A, BE, WEB, BE2);
    k_attn  <<<512,  256, 0, stream>>>(XT, WEB, BE2, S, Z);
    k_w2    <<<512,  256, 0, stream>>>(w_out, S, Z, W2);
    k_w3    <<<256,  256, 0, stream>>>(w_qkv, W2, A, BE, b_out, W3B, B3);
    k_final <<<1024, 256, 0, stream>>>(XT, W3B, B3, out);
}

// Round 6
// 243.683 us; speedup vs baseline: 2.4751x; 1.0384x over previous
//
#include <hip/hip_runtime.h>
#include <hip/hip_bf16.h>

typedef unsigned short ushort_t;
typedef unsigned int uint_t;

#define DIM   256
#define LSEQ  32768
#define HEADS 8
#define CPG   8
#define EPS   1e-5f

typedef float f32x4 __attribute__((ext_vector_type(4)));
typedef short sfrag8 __attribute__((ext_vector_type(8)));

static __device__ __forceinline__ float b2f(ushort_t u) {
    return __uint_as_float((uint_t)u << 16);
}
static __device__ __forceinline__ ushort_t f2bs(float f) {
    union { __hip_bfloat16 h; ushort_t u; } cv;
    cv.h = __float2bfloat16(f);
    return cv.u;
}
static __device__ __forceinline__ uint_t pk2(float a, float b) {
    return (uint_t)f2bs(a) | ((uint_t)f2bs(b) << 16);
}

// ============ fused transpose + group stats: pure-register 4x4 micro-transpose ============
__global__ __launch_bounds__(256) void k_tr(const float* __restrict__ x,
                                            ushort_t* __restrict__ XT,
                                            float* __restrict__ gsum,
                                            float* __restrict__ gsumsq) {
    const int tid   = threadIdx.x;
    const int lane  = tid & 63;
    const int wv    = tid >> 6;
    const int l_blk = lane >> 3;
    const int c_blk = lane & 7;
    const int c0    = (blockIdx.x & 1) * 128;
    const int l0b   = (blockIdx.x >> 1) * 128;
    const int cb    = c0 + 32 * wv + 4 * c_blk;

    const float* xr0 = x + (size_t)(cb + 0) * LSEQ;
    const float* xr1 = x + (size_t)(cb + 1) * LSEQ;
    const float* xr2 = x + (size_t)(cb + 2) * LSEQ;
    const float* xr3 = x + (size_t)(cb + 3) * LSEQ;

    float s = 0.f, s2 = 0.f;

    #pragma unroll
    for (int t = 0; t < 4; t++) {
        const int l = l0b + 32 * t + 4 * l_blk;
        float4 a = *(const float4*)(xr0 + l);
        float4 b = *(const float4*)(xr1 + l);
        float4 c = *(const float4*)(xr2 + l);
        float4 d = *(const float4*)(xr3 + l);

        s  += (a.x + a.y + a.z + a.w) + (b.x + b.y + b.z + b.w)
            + (c.x + c.y + c.z + c.w) + (d.x + d.y + d.z + d.w);
        s2 += (a.x*a.x + a.y*a.y + a.z*a.z + a.w*a.w)
            + (b.x*b.x + b.y*b.y + b.z*b.z + b.w*b.w)
            + (c.x*c.x + c.y*c.y + c.z*c.z + c.w*c.w)
            + (d.x*d.x + d.y*d.y + d.z*d.z + d.w*d.w);

        ushort_t* dst = XT + (size_t)l * 256 + cb;
        uint2 p0; p0.x = pk2(a.x, b.x); p0.y = pk2(c.x, d.x);
        uint2 p1; p1.x = pk2(a.y, b.y); p1.y = pk2(c.y, d.y);
        uint2 p2; p2.x = pk2(a.z, b.z); p2.y = pk2(c.z, d.z);
        uint2 p3; p3.x = pk2(a.w, b.w); p3.y = pk2(c.w, d.w);
        *(uint2*)(dst)           = p0;
        *(uint2*)(dst + 256)     = p1;
        *(uint2*)(dst + 512)     = p2;
        *(uint2*)(dst + 768)     = p3;
    }

    s  += __shfl_xor(s, 1);   s2 += __shfl_xor(s2, 1);
    s  += __shfl_xor(s, 8);   s2 += __shfl_xor(s2, 8);
    s  += __shfl_xor(s, 16);  s2 += __shfl_xor(s2, 16);
    s  += __shfl_xor(s, 32);  s2 += __shfl_xor(s2, 32);
    if (l_blk == 0 && (c_blk & 1) == 0) {
        int g = ((c0 + 32 * wv) >> 3) + (c_blk >> 1);
        atomicAdd(&gsum[g], s);
        atomicAdd(&gsumsq[g], s2);
    }
}

// ============ a[c], bb[c] ============
__global__ void k_ab(const float* __restrict__ gn_w, const float* __restrict__ gn_b,
                     const float* __restrict__ gsum, const float* __restrict__ gsumsq,
                     float* __restrict__ A, float* __restrict__ BB) {
    int c = threadIdx.x;
    int g = c >> 3;
    const float inv_n = 1.f / (float)(CPG * LSEQ);
    float mu  = gsum[g] * inv_n;
    float var = gsumsq[g] * inv_n - mu * mu;
    float inv = rsqrtf(var + EPS);
    float a = gn_w[c] * inv;
    A[c]  = a;
    BB[c] = gn_b[c] - mu * a;
}

// ============ folded qkv biases ============
__global__ void k_fold_b(const float* __restrict__ w_qkv, const float* __restrict__ b_qkv,
                         const float* __restrict__ BB, float* __restrict__ BE) {
    int r = blockIdx.x * 256 + threadIdx.x;   // 1536
    float s = b_qkv[r];
    const float4* wr = (const float4*)(w_qkv + (size_t)r * DIM);
    const float4* bb = (const float4*)BB;
    #pragma unroll 4
    for (int c4 = 0; c4 < 64; c4++) {
        float4 w = wr[c4], b = bb[c4];
        s += w.x*b.x + w.y*b.y + w.z*b.z + w.w*b.w;
    }
    BE[r] = s;
}

// ============ folded k/v weights: WEB bf16 [r'][c], r' = h*128 + part*64 + j ============
__global__ void k_fold_w(const float* __restrict__ w_qkv, const float* __restrict__ A,
                         const float* __restrict__ BE,
                         ushort_t* __restrict__ WEB, float* __restrict__ BE2) {
    int idx = blockIdx.x * 256 + threadIdx.x;   // 262144
    int rp = idx >> 8, c = idx & 255;
    int h = rp >> 7, sub = rp & 127, part = sub >> 6, j = sub & 63;
    int orig = 512 + part * 512 + h * 64 + j;
    WEB[(size_t)rp * 256 + c] = f2bs(w_qkv[(size_t)orig * 256 + c] * A[c]);
    if (c == 0) BE2[rp] = BE[orig];
}

// ============ fused kv-GEMM + exp + context GEMM ============
// grid 512: h = bid>>6 (8 sharers of a superchunk == mod 8 -> same XCD L2),
// superchunk = bid&63 (512 cols, 8 sub-chunks of 64).
// Wave wv owns rows [wv*32, wv*32+32) (2 m-tiles) x all 64 cols (4 n-tiles):
// Af[2][8] = 64 VGPRs (the r5 Af[4][8]=128 spilled to scratch -> 85 MB writes).
__global__ __launch_bounds__(256, 2) void k_attn(const ushort_t* __restrict__ XT,
                                                 const ushort_t* __restrict__ WEB,
                                                 const float* __restrict__ BE2,
                                                 float* __restrict__ S, float* __restrict__ Z) {
    __shared__ __align__(16) ushort_t xs[64 * 264];
    __shared__ __align__(16) ushort_t ek[64 * 72];
    __shared__ __align__(16) ushort_t vv[64 * 72];
    const int tid  = threadIdx.x;
    const int lane = tid & 63;
    const int wv   = __builtin_amdgcn_readfirstlane(tid >> 6);
    const int ln   = lane & 15;
    const int q    = lane >> 4;
    const int h    = blockIdx.x >> 6;
    const int cg0  = (blockIdx.x & 63) * 512;

    const int srow = tid >> 5;
    const int sseg = (tid & 31) * 8;

    sfrag8 Af[2][8];
    #pragma unroll
    for (int mt = 0; mt < 2; mt++) {
        const ushort_t* ap = WEB + (size_t)(h*128 + wv*32 + mt*16 + ln) * 256 + q*8;
        #pragma unroll
        for (int k0 = 0; k0 < 8; k0++) Af[mt][k0] = *(const sfrag8*)(ap + k0*32);
    }
    float bias[2][4];
    #pragma unroll
    for (int mt = 0; mt < 2; mt++)
        #pragma unroll
        for (int r = 0; r < 4; r++)
            bias[mt][r] = BE2[h*128 + wv*32 + mt*16 + q*4 + r];

    f32x4 Sacc[4];
    #pragma unroll
    for (int nt = 0; nt < 4; nt++)
        #pragma unroll
        for (int e = 0; e < 4; e++) Sacc[nt][e] = 0.f;
    float zsum = 0.f;

    uint4 pf[8];
    #pragma unroll
    for (int it = 0; it < 8; it++)
        pf[it] = *(const uint4*)(XT + (size_t)(cg0 + it*8 + srow) * 256 + sseg);

    for (int sc = 0; sc < 8; sc++) {
        #pragma unroll
        for (int it = 0; it < 8; it++)
            *(uint4*)&xs[(it*8 + srow) * 264 + sseg] = pf[it];
        __syncthreads();

        if (sc < 7) {
            const int l0n = cg0 + (sc + 1) * 64;
            #pragma unroll
            for (int it = 0; it < 8; it++)
                pf[it] = *(const uint4*)(XT + (size_t)(l0n + it*8 + srow) * 256 + sseg);
        }

        // GEMM1: 32 rows (2 m-tiles) x 64 cols (4 n-tiles), K=256
        f32x4 acc[2][4];
        #pragma unroll
        for (int mt = 0; mt < 2; mt++)
            #pragma unroll
            for (int nt = 0; nt < 4; nt++)
                #pragma unroll
                for (int e = 0; e < 4; e++) acc[mt][nt][e] = 0.f;

        #pragma unroll
        for (int k0 = 0; k0 < 8; k0++) {
            sfrag8 b0 = *(const sfrag8*)&xs[(0*16 + ln) * 264 + k0*32 + q*8];
            sfrag8 b1 = *(const sfrag8*)&xs[(1*16 + ln) * 264 + k0*32 + q*8];
            sfrag8 b2 = *(const sfrag8*)&xs[(2*16 + ln) * 264 + k0*32 + q*8];
            sfrag8 b3 = *(const sfrag8*)&xs[(3*16 + ln) * 264 + k0*32 + q*8];
            #pragma unroll
            for (int mt = 0; mt < 2; mt++) {
                acc[mt][0] = __builtin_amdgcn_mfma_f32_16x16x32_bf16(Af[mt][k0], b0, acc[mt][0], 0, 0, 0);
                acc[mt][1] = __builtin_amdgcn_mfma_f32_16x16x32_bf16(Af[mt][k0], b1, acc[mt][1], 0, 0, 0);
                acc[mt][2] = __builtin_amdgcn_mfma_f32_16x16x32_bf16(Af[mt][k0], b2, acc[mt][2], 0, 0, 0);
                acc[mt][3] = __builtin_amdgcn_mfma_f32_16x16x32_bf16(Af[mt][k0], b3, acc[mt][3], 0, 0, 0);
            }
        }

        // waves 0,1 -> ek rows 0..63 (with exp); waves 2,3 -> vv rows 0..63
        if (wv < 2) {
            #pragma unroll
            for (int mt = 0; mt < 2; mt++)
                #pragma unroll
                for (int nt = 0; nt < 4; nt++)
                    #pragma unroll
                    for (int r = 0; r < 4; r++) {
                        int row = wv*32 + mt*16 + q*4 + r;
                        int col = nt*16 + ln;
                        ek[row * 72 + col] = f2bs(__expf(acc[mt][nt][r] + bias[mt][r]));
                    }
        } else {
            #pragma unroll
            for (int mt = 0; mt < 2; mt++)
                #pragma unroll
                for (int nt = 0; nt < 4; nt++)
                    #pragma unroll
                    for (int r = 0; r < 4; r++) {
                        int row = (wv-2)*32 + mt*16 + q*4 + r;
                        int col = nt*16 + ln;
                        vv[row * 72 + col] = f2bs(acc[mt][nt][r] + bias[mt][r]);
                    }
        }
        __syncthreads();

        // GEMM2: S += ek @ vv^T (K=64)
        #pragma unroll
        for (int k0 = 0; k0 < 2; k0++) {
            sfrag8 a = *(const sfrag8*)&ek[(wv*16 + ln) * 72 + k0*32 + q*8];
            #pragma unroll
            for (int nt = 0; nt < 4; nt++) {
                sfrag8 b = *(const sfrag8*)&vv[(nt*16 + ln) * 72 + k0*32 + q*8];
                Sacc[nt] = __builtin_amdgcn_mfma_f32_16x16x32_bf16(a, b, Sacc[nt], 0, 0, 0);
            }
        }
        if (wv == 2) {
            float zs = 0.f;
            #pragma unroll 8
            for (int j = 0; j < 64; j++) zs += b2f(ek[lane * 72 + j]);
            zsum += zs;
        }
    }

    float* Sh = S + h * 4096;
    #pragma unroll
    for (int nt = 0; nt < 4; nt++)
        #pragma unroll
        for (int r = 0; r < 4; r++)
            atomicAdd(&Sh[(wv*16 + q*4 + r) * 64 + nt*16 + ln], Sacc[nt][r]);
    if (wv == 2) atomicAdd(&Z[h * 64 + lane], zsum);
}

// ============ W2[d][hc] = sum_e w_out[d][h64+e] * S[hc][e] / Z[hc] ============
__global__ void k_w2(const float* __restrict__ w_out, const float* __restrict__ S,
                     const float* __restrict__ Z, float* __restrict__ W2) {
    int d  = blockIdx.x >> 1;
    int hc = ((blockIdx.x & 1) << 8) + threadIdx.x;
    int h64 = hc & ~63;
    float invZ = 1.f / Z[hc];
    const float4* wo = (const float4*)(w_out + (size_t)d * 512 + h64);
    const float4* Sr = (const float4*)(S + (size_t)hc * 64);
    float s = 0.f;
    #pragma unroll
    for (int e4 = 0; e4 < 16; e4++) {
        float4 a = wo[e4], b = Sr[e4];
        s += a.x*b.x + a.y*b.y + a.z*b.z + a.w*b.w;
    }
    W2[(size_t)d * 512 + hc] = s * invZ;
}

// ============ W3B[d][c] bf16 + B3[d] ============
__global__ void k_w3(const float* __restrict__ w_qkv, const float* __restrict__ W2,
                     const float* __restrict__ A, const float* __restrict__ BE,
                     const float* __restrict__ b_out,
                     ushort_t* __restrict__ W3B, float* __restrict__ B3) {
    int d = blockIdx.x, c = threadIdx.x;
    const float* W2d = W2 + (size_t)d * 512;
    float s = 0.f;
    #pragma unroll 4
    for (int hc = 0; hc < 512; hc++)
        s += W2d[hc] * w_qkv[(size_t)hc * 256 + c];
    W3B[(size_t)d * 256 + c] = f2bs(s * A[c]);
    __shared__ float red[256];
    red[c] = W2d[c] * BE[c] + W2d[256 + c] * BE[256 + c];
    __syncthreads();
    for (int off = 128; off > 0; off >>= 1) {
        if (c < off) red[c] += red[c + off];
        __syncthreads();
    }
    if (c == 0) B3[d] = b_out[d] + red[0];
}

// ============ final GEMM: out = W3B @ xT + b3 ============
// grid 1024: m0 = (bid>>9)*128, chunk = bid&511 (XCD pairing). Wave owns 32 rows x 64 cols.
__global__ __launch_bounds__(256, 2) void k_final(const ushort_t* __restrict__ XT,
                                                  const ushort_t* __restrict__ W3B,
                                                  const float* __restrict__ B3,
                                                  float* __restrict__ out) {
    __shared__ __align__(16) ushort_t xs[64 * 264];
    const int tid  = threadIdx.x;
    const int lane = tid & 63;
    const int wv   = __builtin_amdgcn_readfirstlane(tid >> 6);
    const int ln   = lane & 15;
    const int q    = lane >> 4;
    const int m0   = (blockIdx.x >> 9) * 128;
    const int l0   = (blockIdx.x & 511) * 64;

    sfrag8 Af[2][8];
    #pragma unroll
    for (int mt = 0; mt < 2; mt++) {
        const ushort_t* ap = W3B + (size_t)(m0 + wv*32 + mt*16 + ln) * 256 + q*8;
        #pragma unroll
        for (int k0 = 0; k0 < 8; k0++) Af[mt][k0] = *(const sfrag8*)(ap + k0*32);
    }
    float bias[2][4];
    #pragma unroll
    for (int mt = 0; mt < 2; mt++)
        #pragma unroll
        for (int r = 0; r < 4; r++)
            bias[mt][r] = B3[m0 + wv*32 + mt*16 + q*4 + r];

    #pragma unroll
    for (int it = 0; it < 8; it++) {
        int idx = it * 256 + tid;
        int row = idx >> 5, seg = idx & 31;
        *(uint4*)&xs[row * 264 + seg * 8] =
            *(const uint4*)(XT + (size_t)(l0 + row) * 256 + seg * 8);
    }
    __syncthreads();

    f32x4 acc[2][4];
    #pragma unroll
    for (int mt = 0; mt < 2; mt++)
        #pragma unroll
        for (int nt = 0; nt < 4; nt++)
            #pragma unroll
            for (int e = 0; e < 4; e++) acc[mt][nt][e] = 0.f;

    #pragma unroll
    for (int k0 = 0; k0 < 8; k0++) {
        sfrag8 b0 = *(const sfrag8*)&xs[(0*16 + ln) * 264 + k0*32 + q*8];
        sfrag8 b1 = *(const sfrag8*)&xs[(1*16 + ln) * 264 + k0*32 + q*8];
        sfrag8 b2 = *(const sfrag8*)&xs[(2*16 + ln) * 264 + k0*32 + q*8];
        sfrag8 b3 = *(const sfrag8*)&xs[(3*16 + ln) * 264 + k0*32 + q*8];
        #pragma unroll
        for (int mt = 0; mt < 2; mt++) {
            acc[mt][0] = __builtin_amdgcn_mfma_f32_16x16x32_bf16(Af[mt][k0], b0, acc[mt][0], 0, 0, 0);
            acc[mt][1] = __builtin_amdgcn_mfma_f32_16x16x32_bf16(Af[mt][k0], b1, acc[mt][1], 0, 0, 0);
            acc[mt][2] = __builtin_amdgcn_mfma_f32_16x16x32_bf16(Af[mt][k0], b2, acc[mt][2], 0, 0, 0);
            acc[mt][3] = __builtin_amdgcn_mfma_f32_16x16x32_bf16(Af[mt][k0], b3, acc[mt][3], 0, 0, 0);
        }
    }

    #pragma unroll
    for (int mt = 0; mt < 2; mt++)
        #pragma unroll
        for (int nt = 0; nt < 4; nt++)
            #pragma unroll
            for (int r = 0; r < 4; r++) {
                int row = m0 + wv*32 + mt*16 + q*4 + r;
                int col = l0 + nt*16 + ln;
                out[(size_t)row * LSEQ + col] = acc[mt][nt][r] + bias[mt][r];
            }
}

// ============ launch ============
extern "C" void kernel_launch(void* const* d_in, const int* in_sizes, int n_in,
                              void* d_out, int out_size, void* d_ws, size_t ws_size,
                              hipStream_t stream) {
    const float* x     = (const float*)d_in[0];
    const float* gn_w  = (const float*)d_in[1];
    const float* gn_b  = (const float*)d_in[2];
    const float* w_qkv = (const float*)d_in[3];
    const float* b_qkv = (const float*)d_in[4];
    const float* w_out = (const float*)d_in[5];
    const float* b_out = (const float*)d_in[6];
    float* out = (float*)d_out;
    float* ws  = (float*)d_ws;

    float*    gsum   = ws + 0;        // 32
    float*    gsumsq = ws + 32;       // 32
    float*    S      = ws + 64;       // 32768
    float*    Z      = ws + 32832;    // 512   [zeroed through 33344]
    float*    A      = ws + 33344;    // 256
    float*    BB     = ws + 33600;    // 256
    float*    BE     = ws + 33856;    // 1536
    float*    BE2    = ws + 35392;    // 1024
    ushort_t* WEB    = (ushort_t*)(ws + 36416);    // 1024*256 bf16 (65536 f)
    float*    W2     = ws + 101952;   // 131072
    ushort_t* W3B    = (ushort_t*)(ws + 233024);   // 256*256 bf16 (32768 f)
    float*    B3     = ws + 265792;   // 256
    ushort_t* XT     = (ushort_t*)(ws + 266048);   // 32768*256 bf16 (4194304 f)

    hipMemsetAsync(ws, 0, 33344 * sizeof(float), stream);   // gsum, gsumsq, S, Z
    k_tr    <<<512,  256, 0, stream>>>(x, XT, gsum, gsumsq);
    k_ab    <<<1,    256, 0, stream>>>(gn_w, gn_b, gsum, gsumsq, A, BB);
    k_fold_b<<<6,    256, 0, stream>>>(w_qkv, b_qkv, BB, BE);
    k_fold_w<<<1024, 256, 0, stream>>>(w_qkv, A, BE, WEB, BE2);
    k_attn  <<<512,  256, 0, stream>>>(XT, WEB, BE2, S, Z);
    k_w2    <<<512,  256, 0, stream>>>(w_out, S, Z, W2);
    k_w3    <<<256,  256, 0, stream>>>(w_qkv, W2, A, BE, b_out, W3B, B3);
    k_final <<<1024, 256, 0, stream>>>(XT, W3B, B3, out);
}